// Round 17
// baseline (283.281 us; speedup 1.0000x reference)
//
#include <hip/hip_runtime.h>
#include <hip/hip_bf16.h>

// Problem constants (fixed by setup_inputs)
#define Bq 2
#define Tq 2048
#define Cq 1024
#define Hq 16
#define N3C 3072
#define NROW 4096

typedef __attribute__((ext_vector_type(8))) __bf16 bf16x8;
typedef __attribute__((ext_vector_type(4))) float f32x4;

__device__ __forceinline__ float elu1(float x) {
    return x > 0.0f ? x + 1.0f : __expf(x);
}

// round-to-nearest-even fp32 -> bf16 bits (finite inputs)
__device__ __forceinline__ unsigned short bf16_rne(float v) {
    unsigned int u = __float_as_uint(v);
    u += 0x7FFFu + ((u >> 16) & 1u);
    return (unsigned short)(u >> 16);
}

// ---------------- merged prep: rope table + A split + both B^T splits ----------------
__global__ __launch_bounds__(256) void prep_kernel(
        const float* __restrict__ x, const float* __restrict__ w_attn,
        const float* __restrict__ w_proj,
        float* __restrict__ cosT, float* __restrict__ sinT,
        unsigned short* __restrict__ xhi, unsigned short* __restrict__ xlo,
        unsigned short* __restrict__ wahi, unsigned short* __restrict__ walo,
        unsigned short* __restrict__ wphi, unsigned short* __restrict__ wplo) {
    int blk = blockIdx.x;
    if (blk < 256) {
        int idx = blk * 256 + threadIdx.x;       // < T*32
        int t = idx >> 5;
        int i = idx & 31;
        double inv = pow(10000.0, -(double)i / 32.0);
        double ang = (double)t * inv;
        cosT[idx] = (float)cos(ang);
        sinT[idx] = (float)sin(ang);
    } else if (blk < 256 + 4096) {
        int idx = (blk - 256) * 256 + threadIdx.x;   // < NROW*Cq/4
        float4 v = ((const float4*)x)[idx];
        float a[4] = {v.x, v.y, v.z, v.w};
        unsigned short hb[4], lb[4];
        #pragma unroll
        for (int i = 0; i < 4; ++i) {
            hb[i] = bf16_rne(a[i]);
            float hf = __uint_as_float((unsigned int)hb[i] << 16);
            lb[i] = bf16_rne(a[i] - hf);
        }
        ((ushort4*)xhi)[idx] = make_ushort4(hb[0], hb[1], hb[2], hb[3]);
        ((ushort4*)xlo)[idx] = make_ushort4(lb[0], lb[1], lb[2], lb[3]);
    } else {
        const float* B;
        unsigned short *hi, *lo;
        int bx, by, N;
        if (blk < 256 + 4096 + 3072) {
            int bid = blk - (256 + 4096);
            B = w_attn; hi = wahi; lo = walo; N = N3C;
            bx = bid % 96; by = bid / 96;
        } else {
            int bid = blk - (256 + 4096 + 3072);
            B = w_proj; hi = wphi; lo = wplo; N = Cq;
            bx = bid % 32; by = bid / 32;
        }
        __shared__ float tile[32][33];            // tile[k][n]
        int tx = threadIdx.x & 31, ty = threadIdx.x >> 5;    // ty 0..7
        int k0 = by * 32, n0 = bx * 32;
        #pragma unroll
        for (int i = 0; i < 4; ++i)
            tile[ty + i * 8][tx] = B[(size_t)(k0 + ty + i * 8) * N + n0 + tx];
        __syncthreads();
        // vectorized transposed store: thread covers (n, 4 consecutive k)
        int nl = threadIdx.x >> 3;                // 0..31
        int kq = (threadIdx.x & 7) << 2;          // 0,4,...,28
        unsigned short hb[4], lb[4];
        #pragma unroll
        for (int j = 0; j < 4; ++j) {
            float v = tile[kq + j][nl];
            hb[j] = bf16_rne(v);
            float hf = __uint_as_float((unsigned int)hb[j] << 16);
            lb[j] = bf16_rne(v - hf);
        }
        size_t base = (size_t)(n0 + nl) * Cq + k0 + kq;
        *(ushort4*)(hi + base) = make_ushort4(hb[0], hb[1], hb[2], hb[3]);
        *(ushort4*)(lo + base) = make_ushort4(lb[0], lb[1], lb[2], lb[3]);
    }
}

// ---------------- async global->LDS, 16B per lane ----------------
__device__ __forceinline__ void gload16(const void* g, void* l) {
    __builtin_amdgcn_global_load_lds(
        (const __attribute__((address_space(1))) void*)g,
        (__attribute__((address_space(3))) void*)l, 16, 0, 0);
}

// ---------------- qkv split-3 GEMM, K=1024, fused elu/rope/colsum epilogue ----------------
// R15-proven form: single buffer, 2 barriers/K-tile.
// Tile 128x128, BK=32, 8 waves (4Mx2N), per-wave 32x64 = 2x4 frags, 3 MFMA/frag.
// T2 swizzle both-sides: staging slot ^= (tid>>3)&3 on global source, read slot
// ^= (fr>>1)&3. 512 threads for wave-level latency hiding (R14 win).
__global__ __launch_bounds__(512, 4) void gemm_qkv_kernel(
        const unsigned short* __restrict__ Ahi, const unsigned short* __restrict__ Alo,
        const unsigned short* __restrict__ Bhi, const unsigned short* __restrict__ Blo,
        const float* __restrict__ bias,
        float* __restrict__ Qr, float* __restrict__ Kr, float* __restrict__ Vbuf,
        float* __restrict__ Kpart, const float* __restrict__ cosT,
        const float* __restrict__ sinT) {
    __shared__ unsigned short sAh[128][32];
    __shared__ unsigned short sAl[128][32];
    __shared__ unsigned short sBh[128][32];
    __shared__ unsigned short sBl[128][32];

    const int tid = threadIdx.x;
    const int lane = tid & 63;
    const int wave = tid >> 6;            // 0..7
    const int wr = wave >> 1, wc = wave & 1;   // 4 M-quarters x 2 N-halves
    const int brow = blockIdx.y * 128;
    const int bcol = blockIdx.x * 128;

    const int r_lo = tid >> 2;
    const int skc = (((tid & 3) ^ ((tid >> 3) & 3)) << 3);  // pre-swizzled global k offset

    const int fr = lane & 15;
    const int sgx = (((lane >> 4) ^ ((fr >> 1) & 3)) << 3);  // swizzled read slot
    const int qrow = (lane >> 4) << 2;

    f32x4 acc[2][4];
    #pragma unroll
    for (int i = 0; i < 2; ++i)
        #pragma unroll
        for (int j = 0; j < 4; ++j)
            acc[i][j] = (f32x4){0.0f, 0.0f, 0.0f, 0.0f};

    for (int k0 = 0; k0 < Cq; k0 += 32) {
        size_t ga = (size_t)(brow + r_lo) * Cq + k0 + skc;
        size_t gb = (size_t)(bcol + r_lo) * Cq + k0 + skc;
        gload16(Ahi + ga, &sAh[wave << 4][0]);
        gload16(Alo + ga, &sAl[wave << 4][0]);
        gload16(Bhi + gb, &sBh[wave << 4][0]);
        gload16(Blo + gb, &sBl[wave << 4][0]);
        __syncthreads();

        bf16x8 ah[2], al[2], bh[4], bl[4];
        #pragma unroll
        for (int i = 0; i < 2; ++i) {
            ah[i] = *(const bf16x8*)&sAh[(wr << 5) + (i << 4) + fr][sgx];
            al[i] = *(const bf16x8*)&sAl[(wr << 5) + (i << 4) + fr][sgx];
        }
        #pragma unroll
        for (int j = 0; j < 4; ++j) {
            bh[j] = *(const bf16x8*)&sBh[(wc << 6) + (j << 4) + fr][sgx];
            bl[j] = *(const bf16x8*)&sBl[(wc << 6) + (j << 4) + fr][sgx];
        }
        #pragma unroll
        for (int i = 0; i < 2; ++i)
            #pragma unroll
            for (int j = 0; j < 4; ++j) {
                acc[i][j] = __builtin_amdgcn_mfma_f32_16x16x32_bf16(ah[i], bh[j], acc[i][j], 0, 0, 0);
                acc[i][j] = __builtin_amdgcn_mfma_f32_16x16x32_bf16(ah[i], bl[j], acc[i][j], 0, 0, 0);
                acc[i][j] = __builtin_amdgcn_mfma_f32_16x16x32_bf16(al[i], bh[j], acc[i][j], 0, 0, 0);
            }
        __syncthreads();
    }

    // ---- fused epilogue ----  C/D layout: col = lane&15, row = (lane>>4)*4 + q
    int region = bcol >> 10;                  // 0=Q 1=K 2=V
    if (region == 2) {
        #pragma unroll
        for (int j = 0; j < 4; ++j) {
            int n3 = bcol + (wc << 6) + (j << 4) + fr;
            float bv = bias[n3];
            int nc = n3 & 1023;
            #pragma unroll
            for (int i = 0; i < 2; ++i) {
                int m = brow + (wr << 5) + (i << 4) + qrow;
                #pragma unroll
                for (int q = 0; q < 4; ++q)
                    Vbuf[(size_t)(m + q) * 1024 + nc] = acc[i][j][q] + bv;
            }
        }
    } else {
        float* dst = (region == 0) ? Qr : Kr;
        float colsum[4] = {0.f, 0.f, 0.f, 0.f};
        #pragma unroll
        for (int i = 0; i < 2; ++i) {
            float e[4][4];
            #pragma unroll
            for (int j = 0; j < 4; ++j) {
                float bv = bias[bcol + (wc << 6) + (j << 4) + fr];
                #pragma unroll
                for (int q = 0; q < 4; ++q)
                    e[j][q] = elu1(acc[i][j][q] + bv);
            }
            #pragma unroll
            for (int j = 0; j < 4; ++j) {
                int n3 = bcol + (wc << 6) + (j << 4) + fr;
                int nc = n3 & 1023;
                float sgn = (j < 2) ? -1.0f : 1.0f;
                int fidx = ((j & 1) << 4) + fr;   // (dcol & 31)
                int mbase = brow + (wr << 5) + (i << 4) + qrow;
                #pragma unroll
                for (int q = 0; q < 4; ++q) {
                    int m = mbase + q;
                    int t = m & (Tq - 1);
                    float c = cosT[t * 32 + fidx];
                    float s = sinT[t * 32 + fidx];
                    float r = e[j][q] * c + sgn * e[j ^ 2][q] * s;
                    dst[(size_t)m * 1024 + nc] = r;
                    if (region == 1) colsum[j] += e[j][q];
                }
            }
        }
        if (region == 1) {
            // deterministic per-block column-sum (128 cols x 16 partials)
            float* kred = (float*)&sAh[0][0];     // 8KB = the full sAh
            int slot = (wr << 2) + (lane >> 4);   // 0..15
            #pragma unroll
            for (int j = 0; j < 4; ++j) {
                int cl = (wc << 6) + (j << 4) + fr;
                kred[cl * 16 + slot] = colsum[j];
            }
            __syncthreads();
            if (tid < 128) {
                float s2 = 0.f;
                #pragma unroll
                for (int u = 0; u < 16; ++u) s2 += kred[tid * 16 + u];
                Kpart[(brow >> 7) * 1024 + (bcol & 1023) + tid] = s2;
            }
        }
    }
}

// ---------------- proj split-3 GEMM, K=1024, tile 128x64 (R15-proven) ----------------
__global__ __launch_bounds__(512, 4) void gemm_proj_kernel(
        const unsigned short* __restrict__ Ahi, const unsigned short* __restrict__ Alo,
        const unsigned short* __restrict__ Bhi, const unsigned short* __restrict__ Blo,
        const float* __restrict__ bias, float* __restrict__ C) {
    __shared__ unsigned short sAh[128][32];
    __shared__ unsigned short sAl[128][32];
    __shared__ unsigned short sBh[64][32];
    __shared__ unsigned short sBl[64][32];

    const int tid = threadIdx.x;
    const int lane = tid & 63;
    const int wave = tid >> 6;            // 0..7
    const int wr = wave >> 1, wc = wave & 1;   // 4 M-quarters x 2 N-halves (32 cols each)
    const int brow = blockIdx.y * 128;
    const int bcol = blockIdx.x * 64;

    const int r_lo = tid >> 2;                              // 0..127
    const int skc = (((tid & 3) ^ ((tid >> 3) & 3)) << 3);  // pre-swizzled global k offset

    const int fr = lane & 15;
    const int sgx = (((lane >> 4) ^ ((fr >> 1) & 3)) << 3);
    const int qrow = (lane >> 4) << 2;

    f32x4 acc[2][2];
    #pragma unroll
    for (int i = 0; i < 2; ++i)
        #pragma unroll
        for (int j = 0; j < 2; ++j)
            acc[i][j] = (f32x4){0.0f, 0.0f, 0.0f, 0.0f};

    for (int k0 = 0; k0 < Cq; k0 += 32) {
        size_t ga = (size_t)(brow + r_lo) * Cq + k0 + skc;
        gload16(Ahi + ga, &sAh[wave << 4][0]);
        gload16(Alo + ga, &sAl[wave << 4][0]);
        if (tid < 256) {                                    // 64 B-rows x 4 slots
            size_t gb = (size_t)(bcol + r_lo) * Cq + k0 + skc;
            gload16(Bhi + gb, &sBh[wave << 4][0]);
            gload16(Blo + gb, &sBl[wave << 4][0]);
        }
        __syncthreads();

        bf16x8 ah[2], al[2], bh[2], bl[2];
        #pragma unroll
        for (int i = 0; i < 2; ++i) {
            ah[i] = *(const bf16x8*)&sAh[(wr << 5) + (i << 4) + fr][sgx];
            al[i] = *(const bf16x8*)&sAl[(wr << 5) + (i << 4) + fr][sgx];
        }
        #pragma unroll
        for (int j = 0; j < 2; ++j) {
            bh[j] = *(const bf16x8*)&sBh[(wc << 5) + (j << 4) + fr][sgx];
            bl[j] = *(const bf16x8*)&sBl[(wc << 5) + (j << 4) + fr][sgx];
        }
        #pragma unroll
        for (int i = 0; i < 2; ++i)
            #pragma unroll
            for (int j = 0; j < 2; ++j) {
                acc[i][j] = __builtin_amdgcn_mfma_f32_16x16x32_bf16(ah[i], bh[j], acc[i][j], 0, 0, 0);
                acc[i][j] = __builtin_amdgcn_mfma_f32_16x16x32_bf16(ah[i], bl[j], acc[i][j], 0, 0, 0);
                acc[i][j] = __builtin_amdgcn_mfma_f32_16x16x32_bf16(al[i], bh[j], acc[i][j], 0, 0, 0);
            }
        __syncthreads();
    }

    #pragma unroll
    for (int j = 0; j < 2; ++j) {
        int n = bcol + (wc << 5) + (j << 4) + fr;
        float bv = bias[n];
        #pragma unroll
        for (int i = 0; i < 2; ++i) {
            int m = brow + (wr << 5) + (i << 4) + qrow;
            #pragma unroll
            for (int q = 0; q < 4; ++q)
                C[(size_t)(m + q) * Cq + n] = acc[i][j][q] + bv;
        }
    }
}

// ---------------- KV partial: per (b,h,chunk of 128 rows) ----------------
#define NCH 16
#define CHT (Tq / NCH)    // 128
__global__ __launch_bounds__(256) void kv_kernel(
        const float* __restrict__ Kr, const float* __restrict__ Vbuf,
        float* __restrict__ KVpart) {
    int blk = blockIdx.x;                 // bh*NCH + ch
    int bh = blk >> 4, ch = blk & 15;
    int b = bh >> 4, h = bh & 15;
    int e = threadIdx.x & 63;             // V column
    int dq = threadIdx.x >> 6;            // 0..3 (d quarter); == wave
    int rr = threadIdx.x >> 4;            // 0..15 staging row
    int c8 = threadIdx.x & 15;            // float4 slot within row
    __shared__ float sh[2][2][16][64];    // [buf][K/V][row][col] = 16 KB
    const size_t rb = (size_t)(b * Tq + ch * CHT);
    const size_t coloff = h * 64 + c8 * 4;
    gload16(&Kr[(rb + rr) * 1024 + coloff], &sh[0][0][dq * 4][0]);
    gload16(&Vbuf[(rb + rr) * 1024 + coloff], &sh[0][1][dq * 4][0]);
    __syncthreads();
    float acc[16] = {};
    for (int st = 0; st < 8; ++st) {
        int cur = st & 1;
        if (st < 7) {   // stage next chunk while computing current
            size_t row = rb + (size_t)(st + 1) * 16 + rr;
            gload16(&Kr[row * 1024 + coloff], &sh[cur ^ 1][0][dq * 4][0]);
            gload16(&Vbuf[row * 1024 + coloff], &sh[cur ^ 1][1][dq * 4][0]);
        }
        #pragma unroll
        for (int r = 0; r < 16; ++r) {
            float vv = sh[cur][1][r][e];
            #pragma unroll
            for (int i = 0; i < 16; ++i)
                acc[i] += sh[cur][0][r][dq * 16 + i] * vv;
        }
        __syncthreads();
    }
    float* out = KVpart + (size_t)blk * 4096;
    #pragma unroll
    for (int i = 0; i < 16; ++i) out[(dq * 16 + i) * 64 + e] = acc[i];
}

// ---------------- merged reduce: KV over chunks + Ksum over row-blocks ----------------
__global__ __launch_bounds__(256) void reduce_kernel(
        const float* __restrict__ KVpart, float* __restrict__ KV,
        const float* __restrict__ Kpart, float* __restrict__ Ksum) {
    int gid = blockIdx.x;
    if (gid < 512) {
        int idx = gid * 256 + threadIdx.x;       // < B*H*4096 = 131072
        int bh = idx >> 12;
        int i = idx & 4095;
        float s = 0.f;
        #pragma unroll
        for (int ch = 0; ch < NCH; ++ch) s += KVpart[((size_t)(bh * NCH + ch)) * 4096 + i];
        KV[idx] = s;
    } else {
        int idx = (gid - 512) * 256 + threadIdx.x;    // < 2048
        if (idx >= Bq * 1024) return;
        int b = idx >> 10, c = idx & 1023;
        float s = 0.f;
        #pragma unroll
        for (int mb = 0; mb < 16; ++mb) s += Kpart[(size_t)(b * 16 + mb) * 1024 + c];
        Ksum[idx] = s;
    }
}

// ---------------- y = (Qr @ KV) / denom, 16 rows/block, KV staged per head ----------------
// Halves KV L2 traffic vs 8 rows/block (67 MB total). 4 waves, each 4 rows.
__global__ __launch_bounds__(256) void y_split_kernel(
        const float* __restrict__ Qr, const float* __restrict__ KV,
        const float* __restrict__ Ksum, const float* __restrict__ cosT,
        const float* __restrict__ sinT, unsigned short* __restrict__ hi,
        unsigned short* __restrict__ lo) {
    int row0 = blockIdx.x * 16;           // 16 consecutive rows, same batch b
    int b = row0 >> 11;
    int lane = threadIdx.x & 63, w = threadIdx.x >> 6;
    __shared__ float skv[64][64];         // 16 KB: KV[b,h]
    __shared__ float sq[16][64];          // 4 KB: 16 q-rows of head h
    for (int h = 0; h < Hq; ++h) {
        __syncthreads();                  // protect prev-iter LDS reads
        const float* kvp = KV + (size_t)(b * Hq + h) * 4096;
        #pragma unroll
        for (int i = 0; i < 4; ++i) {
            int idx = threadIdx.x + i * 256;
            ((float4*)skv)[idx] = ((const float4*)kvp)[idx];
        }
        #pragma unroll
        for (int i = 0; i < 4; ++i) {
            int idx = threadIdx.x + i * 256;
            int r = idx >> 6, d = idx & 63;
            sq[r][d] = Qr[(size_t)(row0 + r) * 1024 + h * 64 + d];
        }
        __syncthreads();
        #pragma unroll
        for (int rr = 0; rr < 4; ++rr) {
            int r = (w << 2) + rr;
            int t = (row0 + r) & (Tq - 1);
            float qv = sq[r][lane];
            float c = cosT[t * 32 + (lane & 31)];
            float s = sinT[t * 32 + (lane & 31)];
            float sgn = (lane & 32) ? 1.0f : -1.0f;
            float kc = Ksum[b * 1024 + h * 64 + lane];
            float kp = Ksum[b * 1024 + h * 64 + (lane ^ 32)];
            float dn = qv * (kc * c + sgn * kp * s);
            #pragma unroll
            for (int off = 32; off; off >>= 1) dn += __shfl_xor(dn, off);
            float acc = 0.f;
            #pragma unroll
            for (int d = 0; d < 64; ++d) acc += sq[r][d] * skv[d][lane];
            float v = acc / dn;
            unsigned short hb = bf16_rne(v);
            float hf = __uint_as_float((unsigned int)hb << 16);
            hi[(size_t)(row0 + r) * 1024 + h * 64 + lane] = hb;
            lo[(size_t)(row0 + r) * 1024 + h * 64 + lane] = bf16_rne(v - hf);
        }
    }
}

extern "C" void kernel_launch(void* const* d_in, const int* in_sizes, int n_in,
                              void* d_out, int out_size, void* d_ws, size_t ws_size,
                              hipStream_t stream) {
    const float* x      = (const float*)d_in[0];
    const float* w_attn = (const float*)d_in[1];
    const float* b_attn = (const float*)d_in[2];
    const float* w_proj = (const float*)d_in[3];
    const float* b_proj = (const float*)d_in[4];
    float* out = (float*)d_out;

    float* ws = (float*)d_ws;
    float* Qr    = ws;                           // 4,194,304
    float* Kr    = Qr + (size_t)NROW * Cq;       // 4,194,304
    float* Vb    = Kr + (size_t)NROW * Cq;       // 4,194,304
    float* cosT  = Vb + (size_t)NROW * Cq;       // 65,536
    float* sinT  = cosT + Tq * 32;               // 65,536
    float* Kpart = sinT + Tq * 32;               // 32,768
    float* Ksum  = Kpart + 32 * 1024;            // 2,048
    float* KVp   = Ksum + 2048;                  // 2,097,152 (512*4096)
    float* KV    = KVp + (size_t)512 * 4096;     // 131,072
    unsigned short* xhi  = (unsigned short*)(KV + 131072);   // reused for x then y
    unsigned short* xlo  = xhi + (size_t)NROW * Cq;
    unsigned short* wahi = xlo + (size_t)NROW * Cq;          // 3,145,728
    unsigned short* walo = wahi + (size_t)N3C * Cq;
    unsigned short* wphi = walo + (size_t)N3C * Cq;          // 1,048,576
    unsigned short* wplo = wphi + (size_t)Cq * Cq;

    // 1. merged prep: rope tables + x split + w_attn^T split + w_proj^T split
    prep_kernel<<<256 + 4096 + 3072 + 1024, 256, 0, stream>>>(
        x, w_attn, w_proj, cosT, sinT, xhi, xlo, wahi, walo, wphi, wplo);

    // 2. qkv GEMM (bf16x3) with fused elu+rope epilogue -> Qr, Kr, Vb, Kpart
    gemm_qkv_kernel<<<dim3(N3C / 128, NROW / 128), 512, 0, stream>>>(
        xhi, xlo, wahi, walo, b_attn, Qr, Kr, Vb, Kpart, cosT, sinT);

    // 3. KV = Kr^T @ V per head (async 2-phase staging)
    kv_kernel<<<Bq * Hq * NCH, 256, 0, stream>>>(Kr, Vb, KVp);

    // 4. merged reduce: KV chunks + Ksum row-blocks
    reduce_kernel<<<512 + 8, 256, 0, stream>>>(KVp, KV, Kpart, Ksum);

    // 5. y = Qr @ KV / denom (denom fused), bf16 hi/lo split (A of proj GEMM)
    y_split_kernel<<<NROW / 16, 256, 0, stream>>>(Qr, KV, Ksum, cosT, sinT, xhi, xlo);

    // 6. out = y @ w_proj + b_proj  (128x64 tile, 512 blocks = 2/CU)
    gemm_proj_kernel<<<dim3(Cq / 64, NROW / 128), 512, 0, stream>>>(
        xhi, xlo, wphi, wplo, b_proj, out);
}

// Round 18
// 193.114 us; speedup vs baseline: 1.4669x; 1.4669x over previous
//
#include <hip/hip_runtime.h>
#include <hip/hip_bf16.h>

// Problem constants (fixed by setup_inputs)
#define Bq 2
#define Tq 2048
#define Cq 1024
#define Hq 16
#define N3C 3072
#define NROW 4096

typedef __attribute__((ext_vector_type(8))) __bf16 bf16x8;
typedef __attribute__((ext_vector_type(4))) float f32x4;

__device__ __forceinline__ float elu1(float x) {
    return x > 0.0f ? x + 1.0f : __expf(x);
}

// round-to-nearest-even fp32 -> bf16 bits (finite inputs)
__device__ __forceinline__ unsigned short bf16_rne(float v) {
    unsigned int u = __float_as_uint(v);
    u += 0x7FFFu + ((u >> 16) & 1u);
    return (unsigned short)(u >> 16);
}

// ---------------- merged prep: rope table + A split + both B^T splits ----------------
__global__ __launch_bounds__(256) void prep_kernel(
        const float* __restrict__ x, const float* __restrict__ w_attn,
        const float* __restrict__ w_proj,
        float* __restrict__ cosT, float* __restrict__ sinT,
        unsigned short* __restrict__ xhi, unsigned short* __restrict__ xlo,
        unsigned short* __restrict__ wahi, unsigned short* __restrict__ walo,
        unsigned short* __restrict__ wphi, unsigned short* __restrict__ wplo) {
    int blk = blockIdx.x;
    if (blk < 256) {
        int idx = blk * 256 + threadIdx.x;       // < T*32
        int t = idx >> 5;
        int i = idx & 31;
        double inv = pow(10000.0, -(double)i / 32.0);
        double ang = (double)t * inv;
        cosT[idx] = (float)cos(ang);
        sinT[idx] = (float)sin(ang);
    } else if (blk < 256 + 4096) {
        int idx = (blk - 256) * 256 + threadIdx.x;   // < NROW*Cq/4
        float4 v = ((const float4*)x)[idx];
        float a[4] = {v.x, v.y, v.z, v.w};
        unsigned short hb[4], lb[4];
        #pragma unroll
        for (int i = 0; i < 4; ++i) {
            hb[i] = bf16_rne(a[i]);
            float hf = __uint_as_float((unsigned int)hb[i] << 16);
            lb[i] = bf16_rne(a[i] - hf);
        }
        ((ushort4*)xhi)[idx] = make_ushort4(hb[0], hb[1], hb[2], hb[3]);
        ((ushort4*)xlo)[idx] = make_ushort4(lb[0], lb[1], lb[2], lb[3]);
    } else {
        const float* B;
        unsigned short *hi, *lo;
        int bx, by, N;
        if (blk < 256 + 4096 + 3072) {
            int bid = blk - (256 + 4096);
            B = w_attn; hi = wahi; lo = walo; N = N3C;
            bx = bid % 96; by = bid / 96;
        } else {
            int bid = blk - (256 + 4096 + 3072);
            B = w_proj; hi = wphi; lo = wplo; N = Cq;
            bx = bid % 32; by = bid / 32;
        }
        __shared__ float tile[32][33];            // tile[k][n]
        int tx = threadIdx.x & 31, ty = threadIdx.x >> 5;    // ty 0..7
        int k0 = by * 32, n0 = bx * 32;
        #pragma unroll
        for (int i = 0; i < 4; ++i)
            tile[ty + i * 8][tx] = B[(size_t)(k0 + ty + i * 8) * N + n0 + tx];
        __syncthreads();
        // vectorized transposed store: thread covers (n, 4 consecutive k)
        int nl = threadIdx.x >> 3;                // 0..31
        int kq = (threadIdx.x & 7) << 2;          // 0,4,...,28
        unsigned short hb[4], lb[4];
        #pragma unroll
        for (int j = 0; j < 4; ++j) {
            float v = tile[kq + j][nl];
            hb[j] = bf16_rne(v);
            float hf = __uint_as_float((unsigned int)hb[j] << 16);
            lb[j] = bf16_rne(v - hf);
        }
        size_t base = (size_t)(n0 + nl) * Cq + k0 + kq;
        *(ushort4*)(hi + base) = make_ushort4(hb[0], hb[1], hb[2], hb[3]);
        *(ushort4*)(lo + base) = make_ushort4(lb[0], lb[1], lb[2], lb[3]);
    }
}

// ---------------- async global->LDS, 16B per lane ----------------
__device__ __forceinline__ void gload16(const void* g, void* l) {
    __builtin_amdgcn_global_load_lds(
        (const __attribute__((address_space(1))) void*)g,
        (__attribute__((address_space(3))) void*)l, 16, 0, 0);
}

// ---------------- qkv split-3 GEMM, K=1024, fused elu/rope/colsum epilogue ----------------
// R15-proven form: single buffer, 2 barriers/K-tile.
// Tile 128x128, BK=32, 8 waves (4Mx2N), per-wave 32x64 = 2x4 frags, 3 MFMA/frag.
// T2 swizzle both-sides: staging slot ^= (tid>>3)&3 on global source, read slot
// ^= (fr>>1)&3. 512 threads for wave-level latency hiding (R14 win).
__global__ __launch_bounds__(512, 4) void gemm_qkv_kernel(
        const unsigned short* __restrict__ Ahi, const unsigned short* __restrict__ Alo,
        const unsigned short* __restrict__ Bhi, const unsigned short* __restrict__ Blo,
        const float* __restrict__ bias,
        float* __restrict__ Qr, float* __restrict__ Kr, float* __restrict__ Vbuf,
        float* __restrict__ Kpart, const float* __restrict__ cosT,
        const float* __restrict__ sinT) {
    __shared__ unsigned short sAh[128][32];
    __shared__ unsigned short sAl[128][32];
    __shared__ unsigned short sBh[128][32];
    __shared__ unsigned short sBl[128][32];

    const int tid = threadIdx.x;
    const int lane = tid & 63;
    const int wave = tid >> 6;            // 0..7
    const int wr = wave >> 1, wc = wave & 1;   // 4 M-quarters x 2 N-halves
    const int brow = blockIdx.y * 128;
    const int bcol = blockIdx.x * 128;

    const int r_lo = tid >> 2;
    const int skc = (((tid & 3) ^ ((tid >> 3) & 3)) << 3);  // pre-swizzled global k offset

    const int fr = lane & 15;
    const int sgx = (((lane >> 4) ^ ((fr >> 1) & 3)) << 3);  // swizzled read slot
    const int qrow = (lane >> 4) << 2;

    f32x4 acc[2][4];
    #pragma unroll
    for (int i = 0; i < 2; ++i)
        #pragma unroll
        for (int j = 0; j < 4; ++j)
            acc[i][j] = (f32x4){0.0f, 0.0f, 0.0f, 0.0f};

    for (int k0 = 0; k0 < Cq; k0 += 32) {
        size_t ga = (size_t)(brow + r_lo) * Cq + k0 + skc;
        size_t gb = (size_t)(bcol + r_lo) * Cq + k0 + skc;
        gload16(Ahi + ga, &sAh[wave << 4][0]);
        gload16(Alo + ga, &sAl[wave << 4][0]);
        gload16(Bhi + gb, &sBh[wave << 4][0]);
        gload16(Blo + gb, &sBl[wave << 4][0]);
        __syncthreads();

        bf16x8 ah[2], al[2], bh[4], bl[4];
        #pragma unroll
        for (int i = 0; i < 2; ++i) {
            ah[i] = *(const bf16x8*)&sAh[(wr << 5) + (i << 4) + fr][sgx];
            al[i] = *(const bf16x8*)&sAl[(wr << 5) + (i << 4) + fr][sgx];
        }
        #pragma unroll
        for (int j = 0; j < 4; ++j) {
            bh[j] = *(const bf16x8*)&sBh[(wc << 6) + (j << 4) + fr][sgx];
            bl[j] = *(const bf16x8*)&sBl[(wc << 6) + (j << 4) + fr][sgx];
        }
        #pragma unroll
        for (int i = 0; i < 2; ++i)
            #pragma unroll
            for (int j = 0; j < 4; ++j) {
                acc[i][j] = __builtin_amdgcn_mfma_f32_16x16x32_bf16(ah[i], bh[j], acc[i][j], 0, 0, 0);
                acc[i][j] = __builtin_amdgcn_mfma_f32_16x16x32_bf16(ah[i], bl[j], acc[i][j], 0, 0, 0);
                acc[i][j] = __builtin_amdgcn_mfma_f32_16x16x32_bf16(al[i], bh[j], acc[i][j], 0, 0, 0);
            }
        __syncthreads();
    }

    // ---- fused epilogue ----  C/D layout: col = lane&15, row = (lane>>4)*4 + q
    int region = bcol >> 10;                  // 0=Q 1=K 2=V
    if (region == 2) {
        #pragma unroll
        for (int j = 0; j < 4; ++j) {
            int n3 = bcol + (wc << 6) + (j << 4) + fr;
            float bv = bias[n3];
            int nc = n3 & 1023;
            #pragma unroll
            for (int i = 0; i < 2; ++i) {
                int m = brow + (wr << 5) + (i << 4) + qrow;
                #pragma unroll
                for (int q = 0; q < 4; ++q)
                    Vbuf[(size_t)(m + q) * 1024 + nc] = acc[i][j][q] + bv;
            }
        }
    } else {
        float* dst = (region == 0) ? Qr : Kr;
        float colsum[4] = {0.f, 0.f, 0.f, 0.f};
        #pragma unroll
        for (int i = 0; i < 2; ++i) {
            float e[4][4];
            #pragma unroll
            for (int j = 0; j < 4; ++j) {
                float bv = bias[bcol + (wc << 6) + (j << 4) + fr];
                #pragma unroll
                for (int q = 0; q < 4; ++q)
                    e[j][q] = elu1(acc[i][j][q] + bv);
            }
            #pragma unroll
            for (int j = 0; j < 4; ++j) {
                int n3 = bcol + (wc << 6) + (j << 4) + fr;
                int nc = n3 & 1023;
                float sgn = (j < 2) ? -1.0f : 1.0f;
                int fidx = ((j & 1) << 4) + fr;   // (dcol & 31)
                int mbase = brow + (wr << 5) + (i << 4) + qrow;
                #pragma unroll
                for (int q = 0; q < 4; ++q) {
                    int m = mbase + q;
                    int t = m & (Tq - 1);
                    float c = cosT[t * 32 + fidx];
                    float s = sinT[t * 32 + fidx];
                    float r = e[j][q] * c + sgn * e[j ^ 2][q] * s;
                    dst[(size_t)m * 1024 + nc] = r;
                    if (region == 1) colsum[j] += e[j][q];
                }
            }
        }
        if (region == 1) {
            // deterministic per-block column-sum (128 cols x 16 partials)
            float* kred = (float*)&sAh[0][0];     // 8KB = the full sAh
            int slot = (wr << 2) + (lane >> 4);   // 0..15
            #pragma unroll
            for (int j = 0; j < 4; ++j) {
                int cl = (wc << 6) + (j << 4) + fr;
                kred[cl * 16 + slot] = colsum[j];
            }
            __syncthreads();
            if (tid < 128) {
                float s2 = 0.f;
                #pragma unroll
                for (int u = 0; u < 16; ++u) s2 += kred[tid * 16 + u];
                Kpart[(brow >> 7) * 1024 + (bcol & 1023) + tid] = s2;
            }
        }
    }
}

// ---------------- proj split-3 GEMM, K=1024, tile 128x64 (R15-proven) ----------------
__global__ __launch_bounds__(512, 4) void gemm_proj_kernel(
        const unsigned short* __restrict__ Ahi, const unsigned short* __restrict__ Alo,
        const unsigned short* __restrict__ Bhi, const unsigned short* __restrict__ Blo,
        const float* __restrict__ bias, float* __restrict__ C) {
    __shared__ unsigned short sAh[128][32];
    __shared__ unsigned short sAl[128][32];
    __shared__ unsigned short sBh[64][32];
    __shared__ unsigned short sBl[64][32];

    const int tid = threadIdx.x;
    const int lane = tid & 63;
    const int wave = tid >> 6;            // 0..7
    const int wr = wave >> 1, wc = wave & 1;   // 4 M-quarters x 2 N-halves (32 cols each)
    const int brow = blockIdx.y * 128;
    const int bcol = blockIdx.x * 64;

    const int r_lo = tid >> 2;                              // 0..127
    const int skc = (((tid & 3) ^ ((tid >> 3) & 3)) << 3);  // pre-swizzled global k offset

    const int fr = lane & 15;
    const int sgx = (((lane >> 4) ^ ((fr >> 1) & 3)) << 3);
    const int qrow = (lane >> 4) << 2;

    f32x4 acc[2][2];
    #pragma unroll
    for (int i = 0; i < 2; ++i)
        #pragma unroll
        for (int j = 0; j < 2; ++j)
            acc[i][j] = (f32x4){0.0f, 0.0f, 0.0f, 0.0f};

    for (int k0 = 0; k0 < Cq; k0 += 32) {
        size_t ga = (size_t)(brow + r_lo) * Cq + k0 + skc;
        gload16(Ahi + ga, &sAh[wave << 4][0]);
        gload16(Alo + ga, &sAl[wave << 4][0]);
        if (tid < 256) {                                    // 64 B-rows x 4 slots
            size_t gb = (size_t)(bcol + r_lo) * Cq + k0 + skc;
            gload16(Bhi + gb, &sBh[wave << 4][0]);
            gload16(Blo + gb, &sBl[wave << 4][0]);
        }
        __syncthreads();

        bf16x8 ah[2], al[2], bh[2], bl[2];
        #pragma unroll
        for (int i = 0; i < 2; ++i) {
            ah[i] = *(const bf16x8*)&sAh[(wr << 5) + (i << 4) + fr][sgx];
            al[i] = *(const bf16x8*)&sAl[(wr << 5) + (i << 4) + fr][sgx];
        }
        #pragma unroll
        for (int j = 0; j < 2; ++j) {
            bh[j] = *(const bf16x8*)&sBh[(wc << 5) + (j << 4) + fr][sgx];
            bl[j] = *(const bf16x8*)&sBl[(wc << 5) + (j << 4) + fr][sgx];
        }
        #pragma unroll
        for (int i = 0; i < 2; ++i)
            #pragma unroll
            for (int j = 0; j < 2; ++j) {
                acc[i][j] = __builtin_amdgcn_mfma_f32_16x16x32_bf16(ah[i], bh[j], acc[i][j], 0, 0, 0);
                acc[i][j] = __builtin_amdgcn_mfma_f32_16x16x32_bf16(ah[i], bl[j], acc[i][j], 0, 0, 0);
                acc[i][j] = __builtin_amdgcn_mfma_f32_16x16x32_bf16(al[i], bh[j], acc[i][j], 0, 0, 0);
            }
        __syncthreads();
    }

    #pragma unroll
    for (int j = 0; j < 2; ++j) {
        int n = bcol + (wc << 5) + (j << 4) + fr;
        float bv = bias[n];
        #pragma unroll
        for (int i = 0; i < 2; ++i) {
            int m = brow + (wr << 5) + (i << 4) + qrow;
            #pragma unroll
            for (int q = 0; q < 4; ++q)
                C[(size_t)(m + q) * Cq + n] = acc[i][j][q] + bv;
        }
    }
}

// ---------------- KV partial: per (b,h,chunk of 128 rows) ----------------
#define NCH 16
#define CHT (Tq / NCH)    // 128
__global__ __launch_bounds__(256) void kv_kernel(
        const float* __restrict__ Kr, const float* __restrict__ Vbuf,
        float* __restrict__ KVpart) {
    int blk = blockIdx.x;                 // bh*NCH + ch
    int bh = blk >> 4, ch = blk & 15;
    int b = bh >> 4, h = bh & 15;
    int e = threadIdx.x & 63;             // V column
    int dq = threadIdx.x >> 6;            // 0..3 (d quarter); == wave
    int rr = threadIdx.x >> 4;            // 0..15 staging row
    int c8 = threadIdx.x & 15;            // float4 slot within row
    __shared__ float sh[2][2][16][64];    // [buf][K/V][row][col] = 16 KB
    const size_t rb = (size_t)(b * Tq + ch * CHT);
    const size_t coloff = h * 64 + c8 * 4;
    gload16(&Kr[(rb + rr) * 1024 + coloff], &sh[0][0][dq * 4][0]);
    gload16(&Vbuf[(rb + rr) * 1024 + coloff], &sh[0][1][dq * 4][0]);
    __syncthreads();
    float acc[16] = {};
    for (int st = 0; st < 8; ++st) {
        int cur = st & 1;
        if (st < 7) {   // stage next chunk while computing current
            size_t row = rb + (size_t)(st + 1) * 16 + rr;
            gload16(&Kr[row * 1024 + coloff], &sh[cur ^ 1][0][dq * 4][0]);
            gload16(&Vbuf[row * 1024 + coloff], &sh[cur ^ 1][1][dq * 4][0]);
        }
        #pragma unroll
        for (int r = 0; r < 16; ++r) {
            float vv = sh[cur][1][r][e];
            #pragma unroll
            for (int i = 0; i < 16; ++i)
                acc[i] += sh[cur][0][r][dq * 16 + i] * vv;
        }
        __syncthreads();
    }
    float* out = KVpart + (size_t)blk * 4096;
    #pragma unroll
    for (int i = 0; i < 16; ++i) out[(dq * 16 + i) * 64 + e] = acc[i];
}

// ---------------- merged reduce: KV over chunks + Ksum over row-blocks ----------------
__global__ __launch_bounds__(256) void reduce_kernel(
        const float* __restrict__ KVpart, float* __restrict__ KV,
        const float* __restrict__ Kpart, float* __restrict__ Ksum) {
    int gid = blockIdx.x;
    if (gid < 512) {
        int idx = gid * 256 + threadIdx.x;       // < B*H*4096 = 131072
        int bh = idx >> 12;
        int i = idx & 4095;
        float s = 0.f;
        #pragma unroll
        for (int ch = 0; ch < NCH; ++ch) s += KVpart[((size_t)(bh * NCH + ch)) * 4096 + i];
        KV[idx] = s;
    } else {
        int idx = (gid - 512) * 256 + threadIdx.x;    // < 2048
        if (idx >= Bq * 1024) return;
        int b = idx >> 10, c = idx & 1023;
        float s = 0.f;
        #pragma unroll
        for (int mb = 0; mb < 16; ++mb) s += Kpart[(size_t)(b * 16 + mb) * 1024 + c];
        Ksum[idx] = s;
    }
}

// ---------------- y = (Qr @ KV) / denom, 8 rows/block, KV staged per head ----------------
// R15/R16-proven form (2 rows/wave keeps the d-loop batch-unrolled; 4 rows/wave
// made the compiler emit a serial LDS-load chain -- R17 regression, VGPR=32 tell).
__global__ __launch_bounds__(256) void y_split_kernel(
        const float* __restrict__ Qr, const float* __restrict__ KV,
        const float* __restrict__ Ksum, const float* __restrict__ cosT,
        const float* __restrict__ sinT, unsigned short* __restrict__ hi,
        unsigned short* __restrict__ lo) {
    int row0 = blockIdx.x * 8;            // 8 consecutive rows, same batch b
    int b = row0 >> 11;
    int lane = threadIdx.x & 63, w = threadIdx.x >> 6;
    __shared__ float skv[64][64];         // 16 KB: KV[b,h]
    __shared__ float sq[8][64];           // 2 KB: 8 q-rows of head h
    for (int h = 0; h < Hq; ++h) {
        __syncthreads();                  // protect prev-iter LDS reads
        const float* kvp = KV + (size_t)(b * Hq + h) * 4096;
        #pragma unroll
        for (int i = 0; i < 4; ++i) {
            int idx = threadIdx.x + i * 256;
            ((float4*)skv)[idx] = ((const float4*)kvp)[idx];
        }
        #pragma unroll
        for (int i = 0; i < 2; ++i) {
            int idx = threadIdx.x + i * 256;
            int r = idx >> 6, d = idx & 63;
            sq[r][d] = Qr[(size_t)(row0 + r) * 1024 + h * 64 + d];
        }
        __syncthreads();
        #pragma unroll
        for (int rr = 0; rr < 2; ++rr) {
            int r = (w << 1) + rr;
            int t = (row0 + r) & (Tq - 1);
            float qv = sq[r][lane];
            float c = cosT[t * 32 + (lane & 31)];
            float s = sinT[t * 32 + (lane & 31)];
            float sgn = (lane & 32) ? 1.0f : -1.0f;
            float kc = Ksum[b * 1024 + h * 64 + lane];
            float kp = Ksum[b * 1024 + h * 64 + (lane ^ 32)];
            float dn = qv * (kc * c + sgn * kp * s);
            #pragma unroll
            for (int off = 32; off; off >>= 1) dn += __shfl_xor(dn, off);
            float acc = 0.f;
            #pragma unroll
            for (int d = 0; d < 64; ++d) acc += sq[r][d] * skv[d][lane];
            float v = acc / dn;
            unsigned short hb = bf16_rne(v);
            float hf = __uint_as_float((unsigned int)hb << 16);
            hi[(size_t)(row0 + r) * 1024 + h * 64 + lane] = hb;
            lo[(size_t)(row0 + r) * 1024 + h * 64 + lane] = bf16_rne(v - hf);
        }
    }
}

extern "C" void kernel_launch(void* const* d_in, const int* in_sizes, int n_in,
                              void* d_out, int out_size, void* d_ws, size_t ws_size,
                              hipStream_t stream) {
    const float* x      = (const float*)d_in[0];
    const float* w_attn = (const float*)d_in[1];
    const float* b_attn = (const float*)d_in[2];
    const float* w_proj = (const float*)d_in[3];
    const float* b_proj = (const float*)d_in[4];
    float* out = (float*)d_out;

    float* ws = (float*)d_ws;
    float* Qr    = ws;                           // 4,194,304
    float* Kr    = Qr + (size_t)NROW * Cq;       // 4,194,304
    float* Vb    = Kr + (size_t)NROW * Cq;       // 4,194,304
    float* cosT  = Vb + (size_t)NROW * Cq;       // 65,536
    float* sinT  = cosT + Tq * 32;               // 65,536
    float* Kpart = sinT + Tq * 32;               // 32,768
    float* Ksum  = Kpart + 32 * 1024;            // 2,048
    float* KVp   = Ksum + 2048;                  // 2,097,152 (512*4096)
    float* KV    = KVp + (size_t)512 * 4096;     // 131,072
    unsigned short* xhi  = (unsigned short*)(KV + 131072);   // reused for x then y
    unsigned short* xlo  = xhi + (size_t)NROW * Cq;
    unsigned short* wahi = xlo + (size_t)NROW * Cq;          // 3,145,728
    unsigned short* walo = wahi + (size_t)N3C * Cq;
    unsigned short* wphi = walo + (size_t)N3C * Cq;          // 1,048,576
    unsigned short* wplo = wphi + (size_t)Cq * Cq;

    // 1. merged prep: rope tables + x split + w_attn^T split + w_proj^T split
    prep_kernel<<<256 + 4096 + 3072 + 1024, 256, 0, stream>>>(
        x, w_attn, w_proj, cosT, sinT, xhi, xlo, wahi, walo, wphi, wplo);

    // 2. qkv GEMM (bf16x3) with fused elu+rope epilogue -> Qr, Kr, Vb, Kpart
    gemm_qkv_kernel<<<dim3(N3C / 128, NROW / 128), 512, 0, stream>>>(
        xhi, xlo, wahi, walo, b_attn, Qr, Kr, Vb, Kpart, cosT, sinT);

    // 3. KV = Kr^T @ V per head (async 2-phase staging)
    kv_kernel<<<Bq * Hq * NCH, 256, 0, stream>>>(Kr, Vb, KVp);

    // 4. merged reduce: KV chunks + Ksum row-blocks
    reduce_kernel<<<512 + 8, 256, 0, stream>>>(KVp, KV, Kpart, Ksum);

    // 5. y = Qr @ KV / denom (denom fused), bf16 hi/lo split (A of proj GEMM)
    y_split_kernel<<<NROW / 8, 256, 0, stream>>>(Qr, KV, Ksum, cosT, sinT, xhi, xlo);

    // 6. out = y @ w_proj + b_proj  (128x64 tile, 512 blocks = 2/CU)
    gemm_proj_kernel<<<dim3(Cq / 64, NROW / 128), 512, 0, stream>>>(
        xhi, xlo, wphi, wplo, b_proj, out);
}

// Round 19
// 181.248 us; speedup vs baseline: 1.5629x; 1.0655x over previous
//
#include <hip/hip_runtime.h>
#include <hip/hip_bf16.h>

// Problem constants (fixed by setup_inputs)
#define Bq 2
#define Tq 2048
#define Cq 1024
#define Hq 16
#define N3C 3072
#define NROW 4096

typedef __attribute__((ext_vector_type(8))) __bf16 bf16x8;
typedef __attribute__((ext_vector_type(4))) float f32x4;

__device__ __forceinline__ float elu1(float x) {
    return x > 0.0f ? x + 1.0f : __expf(x);
}

// round-to-nearest-even fp32 -> bf16 bits (finite inputs)
__device__ __forceinline__ unsigned short bf16_rne(float v) {
    unsigned int u = __float_as_uint(v);
    u += 0x7FFFu + ((u >> 16) & 1u);
    return (unsigned short)(u >> 16);
}

// ---------------- merged prep: rope table + A split + both B^T splits ----------------
__global__ __launch_bounds__(256) void prep_kernel(
        const float* __restrict__ x, const float* __restrict__ w_attn,
        const float* __restrict__ w_proj,
        float* __restrict__ cosT, float* __restrict__ sinT,
        unsigned short* __restrict__ xhi, unsigned short* __restrict__ xlo,
        unsigned short* __restrict__ wahi, unsigned short* __restrict__ walo,
        unsigned short* __restrict__ wphi, unsigned short* __restrict__ wplo) {
    int blk = blockIdx.x;
    if (blk < 256) {
        int idx = blk * 256 + threadIdx.x;       // < T*32
        int t = idx >> 5;
        int i = idx & 31;
        double inv = pow(10000.0, -(double)i / 32.0);
        double ang = (double)t * inv;
        cosT[idx] = (float)cos(ang);
        sinT[idx] = (float)sin(ang);
    } else if (blk < 256 + 4096) {
        int idx = (blk - 256) * 256 + threadIdx.x;   // < NROW*Cq/4
        float4 v = ((const float4*)x)[idx];
        float a[4] = {v.x, v.y, v.z, v.w};
        unsigned short hb[4], lb[4];
        #pragma unroll
        for (int i = 0; i < 4; ++i) {
            hb[i] = bf16_rne(a[i]);
            float hf = __uint_as_float((unsigned int)hb[i] << 16);
            lb[i] = bf16_rne(a[i] - hf);
        }
        ((ushort4*)xhi)[idx] = make_ushort4(hb[0], hb[1], hb[2], hb[3]);
        ((ushort4*)xlo)[idx] = make_ushort4(lb[0], lb[1], lb[2], lb[3]);
    } else {
        const float* B;
        unsigned short *hi, *lo;
        int bx, by, N;
        if (blk < 256 + 4096 + 3072) {
            int bid = blk - (256 + 4096);
            B = w_attn; hi = wahi; lo = walo; N = N3C;
            bx = bid % 96; by = bid / 96;
        } else {
            int bid = blk - (256 + 4096 + 3072);
            B = w_proj; hi = wphi; lo = wplo; N = Cq;
            bx = bid % 32; by = bid / 32;
        }
        __shared__ float tile[32][33];            // tile[k][n]
        int tx = threadIdx.x & 31, ty = threadIdx.x >> 5;    // ty 0..7
        int k0 = by * 32, n0 = bx * 32;
        #pragma unroll
        for (int i = 0; i < 4; ++i)
            tile[ty + i * 8][tx] = B[(size_t)(k0 + ty + i * 8) * N + n0 + tx];
        __syncthreads();
        // vectorized transposed store: thread covers (n, 4 consecutive k)
        int nl = threadIdx.x >> 3;                // 0..31
        int kq = (threadIdx.x & 7) << 2;          // 0,4,...,28
        unsigned short hb[4], lb[4];
        #pragma unroll
        for (int j = 0; j < 4; ++j) {
            float v = tile[kq + j][nl];
            hb[j] = bf16_rne(v);
            float hf = __uint_as_float((unsigned int)hb[j] << 16);
            lb[j] = bf16_rne(v - hf);
        }
        size_t base = (size_t)(n0 + nl) * Cq + k0 + kq;
        *(ushort4*)(hi + base) = make_ushort4(hb[0], hb[1], hb[2], hb[3]);
        *(ushort4*)(lo + base) = make_ushort4(lb[0], lb[1], lb[2], lb[3]);
    }
}

// ---------------- async global->LDS, 16B per lane ----------------
__device__ __forceinline__ void gload16(const void* g, void* l) {
    __builtin_amdgcn_global_load_lds(
        (const __attribute__((address_space(1))) void*)g,
        (__attribute__((address_space(3))) void*)l, 16, 0, 0);
}

// ---------------- qkv split-3 GEMM, K=1024, fused elu/rope/colsum epilogue ----------------
// BK=64 variant of the proven 2-barrier template: each stream stored as two
// 32-col LDS planes [2][128][32]; 8 gloads/thread/K-tile; barrier count HALVED
// (32 vs 64) and compute phase per drain doubled (48 MFMA/wave).
// Tile 128x128, 8 waves (4Mx2N), per-wave 32x64 = 2x4 frags, 3 MFMA/frag.
// T2 swizzle both-sides (per 32-col plane): staging slot ^= (tid>>3)&3 on the
// global source, read slot ^= (fr>>1)&3. LDS 64 KB -> 2 blocks/CU x 8 waves.
__global__ __launch_bounds__(512, 4) void gemm_qkv_kernel(
        const unsigned short* __restrict__ Ahi, const unsigned short* __restrict__ Alo,
        const unsigned short* __restrict__ Bhi, const unsigned short* __restrict__ Blo,
        const float* __restrict__ bias,
        float* __restrict__ Qr, float* __restrict__ Kr, float* __restrict__ Vbuf,
        float* __restrict__ Kpart, const float* __restrict__ cosT,
        const float* __restrict__ sinT) {
    __shared__ unsigned short sAh[2][128][32];
    __shared__ unsigned short sAl[2][128][32];
    __shared__ unsigned short sBh[2][128][32];
    __shared__ unsigned short sBl[2][128][32];

    const int tid = threadIdx.x;
    const int lane = tid & 63;
    const int wave = tid >> 6;            // 0..7
    const int wr = wave >> 1, wc = wave & 1;   // 4 M-quarters x 2 N-halves
    const int brow = blockIdx.y * 128;
    const int bcol = blockIdx.x * 128;

    const int r_lo = tid >> 2;
    const int skc = (((tid & 3) ^ ((tid >> 3) & 3)) << 3);  // pre-swizzled global k offset

    const int fr = lane & 15;
    const int sgx = (((lane >> 4) ^ ((fr >> 1) & 3)) << 3);  // swizzled read slot
    const int qrow = (lane >> 4) << 2;

    f32x4 acc[2][4];
    #pragma unroll
    for (int i = 0; i < 2; ++i)
        #pragma unroll
        for (int j = 0; j < 4; ++j)
            acc[i][j] = (f32x4){0.0f, 0.0f, 0.0f, 0.0f};

    for (int k0 = 0; k0 < Cq; k0 += 64) {
        size_t ga = (size_t)(brow + r_lo) * Cq + k0 + skc;
        size_t gb = (size_t)(bcol + r_lo) * Cq + k0 + skc;
        gload16(Ahi + ga, &sAh[0][wave << 4][0]);
        gload16(Ahi + ga + 32, &sAh[1][wave << 4][0]);
        gload16(Alo + ga, &sAl[0][wave << 4][0]);
        gload16(Alo + ga + 32, &sAl[1][wave << 4][0]);
        gload16(Bhi + gb, &sBh[0][wave << 4][0]);
        gload16(Bhi + gb + 32, &sBh[1][wave << 4][0]);
        gload16(Blo + gb, &sBl[0][wave << 4][0]);
        gload16(Blo + gb + 32, &sBl[1][wave << 4][0]);
        __syncthreads();

        #pragma unroll
        for (int kh = 0; kh < 2; ++kh) {
            bf16x8 ah[2], al[2], bh[4], bl[4];
            #pragma unroll
            for (int i = 0; i < 2; ++i) {
                ah[i] = *(const bf16x8*)&sAh[kh][(wr << 5) + (i << 4) + fr][sgx];
                al[i] = *(const bf16x8*)&sAl[kh][(wr << 5) + (i << 4) + fr][sgx];
            }
            #pragma unroll
            for (int j = 0; j < 4; ++j) {
                bh[j] = *(const bf16x8*)&sBh[kh][(wc << 6) + (j << 4) + fr][sgx];
                bl[j] = *(const bf16x8*)&sBl[kh][(wc << 6) + (j << 4) + fr][sgx];
            }
            #pragma unroll
            for (int i = 0; i < 2; ++i)
                #pragma unroll
                for (int j = 0; j < 4; ++j) {
                    acc[i][j] = __builtin_amdgcn_mfma_f32_16x16x32_bf16(ah[i], bh[j], acc[i][j], 0, 0, 0);
                    acc[i][j] = __builtin_amdgcn_mfma_f32_16x16x32_bf16(ah[i], bl[j], acc[i][j], 0, 0, 0);
                    acc[i][j] = __builtin_amdgcn_mfma_f32_16x16x32_bf16(al[i], bh[j], acc[i][j], 0, 0, 0);
                }
        }
        __syncthreads();
    }

    // ---- fused epilogue ----  C/D layout: col = lane&15, row = (lane>>4)*4 + q
    int region = bcol >> 10;                  // 0=Q 1=K 2=V
    if (region == 2) {
        #pragma unroll
        for (int j = 0; j < 4; ++j) {
            int n3 = bcol + (wc << 6) + (j << 4) + fr;
            float bv = bias[n3];
            int nc = n3 & 1023;
            #pragma unroll
            for (int i = 0; i < 2; ++i) {
                int m = brow + (wr << 5) + (i << 4) + qrow;
                #pragma unroll
                for (int q = 0; q < 4; ++q)
                    Vbuf[(size_t)(m + q) * 1024 + nc] = acc[i][j][q] + bv;
            }
        }
    } else {
        float* dst = (region == 0) ? Qr : Kr;
        float colsum[4] = {0.f, 0.f, 0.f, 0.f};
        #pragma unroll
        for (int i = 0; i < 2; ++i) {
            float e[4][4];
            #pragma unroll
            for (int j = 0; j < 4; ++j) {
                float bv = bias[bcol + (wc << 6) + (j << 4) + fr];
                #pragma unroll
                for (int q = 0; q < 4; ++q)
                    e[j][q] = elu1(acc[i][j][q] + bv);
            }
            #pragma unroll
            for (int j = 0; j < 4; ++j) {
                int n3 = bcol + (wc << 6) + (j << 4) + fr;
                int nc = n3 & 1023;
                float sgn = (j < 2) ? -1.0f : 1.0f;
                int fidx = ((j & 1) << 4) + fr;   // (dcol & 31)
                int mbase = brow + (wr << 5) + (i << 4) + qrow;
                #pragma unroll
                for (int q = 0; q < 4; ++q) {
                    int m = mbase + q;
                    int t = m & (Tq - 1);
                    float c = cosT[t * 32 + fidx];
                    float s = sinT[t * 32 + fidx];
                    float r = e[j][q] * c + sgn * e[j ^ 2][q] * s;
                    dst[(size_t)m * 1024 + nc] = r;
                    if (region == 1) colsum[j] += e[j][q];
                }
            }
        }
        if (region == 1) {
            // deterministic per-block column-sum (128 cols x 16 partials)
            float* kred = (float*)&sAh[0][0][0];  // 8KB of the 16KB sAh
            int slot = (wr << 2) + (lane >> 4);   // 0..15
            #pragma unroll
            for (int j = 0; j < 4; ++j) {
                int cl = (wc << 6) + (j << 4) + fr;
                kred[cl * 16 + slot] = colsum[j];
            }
            __syncthreads();
            if (tid < 128) {
                float s2 = 0.f;
                #pragma unroll
                for (int u = 0; u < 16; ++u) s2 += kred[tid * 16 + u];
                Kpart[(brow >> 7) * 1024 + (bcol & 1023) + tid] = s2;
            }
        }
    }
}

// ---------------- proj split-3 GEMM, K=1024, tile 128x64 (R15-proven) ----------------
__global__ __launch_bounds__(512, 4) void gemm_proj_kernel(
        const unsigned short* __restrict__ Ahi, const unsigned short* __restrict__ Alo,
        const unsigned short* __restrict__ Bhi, const unsigned short* __restrict__ Blo,
        const float* __restrict__ bias, float* __restrict__ C) {
    __shared__ unsigned short sAh[128][32];
    __shared__ unsigned short sAl[128][32];
    __shared__ unsigned short sBh[64][32];
    __shared__ unsigned short sBl[64][32];

    const int tid = threadIdx.x;
    const int lane = tid & 63;
    const int wave = tid >> 6;            // 0..7
    const int wr = wave >> 1, wc = wave & 1;   // 4 M-quarters x 2 N-halves (32 cols each)
    const int brow = blockIdx.y * 128;
    const int bcol = blockIdx.x * 64;

    const int r_lo = tid >> 2;                              // 0..127
    const int skc = (((tid & 3) ^ ((tid >> 3) & 3)) << 3);  // pre-swizzled global k offset

    const int fr = lane & 15;
    const int sgx = (((lane >> 4) ^ ((fr >> 1) & 3)) << 3);
    const int qrow = (lane >> 4) << 2;

    f32x4 acc[2][2];
    #pragma unroll
    for (int i = 0; i < 2; ++i)
        #pragma unroll
        for (int j = 0; j < 2; ++j)
            acc[i][j] = (f32x4){0.0f, 0.0f, 0.0f, 0.0f};

    for (int k0 = 0; k0 < Cq; k0 += 32) {
        size_t ga = (size_t)(brow + r_lo) * Cq + k0 + skc;
        gload16(Ahi + ga, &sAh[wave << 4][0]);
        gload16(Alo + ga, &sAl[wave << 4][0]);
        if (tid < 256) {                                    // 64 B-rows x 4 slots
            size_t gb = (size_t)(bcol + r_lo) * Cq + k0 + skc;
            gload16(Bhi + gb, &sBh[wave << 4][0]);
            gload16(Blo + gb, &sBl[wave << 4][0]);
        }
        __syncthreads();

        bf16x8 ah[2], al[2], bh[2], bl[2];
        #pragma unroll
        for (int i = 0; i < 2; ++i) {
            ah[i] = *(const bf16x8*)&sAh[(wr << 5) + (i << 4) + fr][sgx];
            al[i] = *(const bf16x8*)&sAl[(wr << 5) + (i << 4) + fr][sgx];
        }
        #pragma unroll
        for (int j = 0; j < 2; ++j) {
            bh[j] = *(const bf16x8*)&sBh[(wc << 5) + (j << 4) + fr][sgx];
            bl[j] = *(const bf16x8*)&sBl[(wc << 5) + (j << 4) + fr][sgx];
        }
        #pragma unroll
        for (int i = 0; i < 2; ++i)
            #pragma unroll
            for (int j = 0; j < 2; ++j) {
                acc[i][j] = __builtin_amdgcn_mfma_f32_16x16x32_bf16(ah[i], bh[j], acc[i][j], 0, 0, 0);
                acc[i][j] = __builtin_amdgcn_mfma_f32_16x16x32_bf16(ah[i], bl[j], acc[i][j], 0, 0, 0);
                acc[i][j] = __builtin_amdgcn_mfma_f32_16x16x32_bf16(al[i], bh[j], acc[i][j], 0, 0, 0);
            }
        __syncthreads();
    }

    #pragma unroll
    for (int j = 0; j < 2; ++j) {
        int n = bcol + (wc << 5) + (j << 4) + fr;
        float bv = bias[n];
        #pragma unroll
        for (int i = 0; i < 2; ++i) {
            int m = brow + (wr << 5) + (i << 4) + qrow;
            #pragma unroll
            for (int q = 0; q < 4; ++q)
                C[(size_t)(m + q) * Cq + n] = acc[i][j][q] + bv;
        }
    }
}

// ---------------- KV partial: per (b,h,chunk of 128 rows) ----------------
#define NCH 16
#define CHT (Tq / NCH)    // 128
__global__ __launch_bounds__(256) void kv_kernel(
        const float* __restrict__ Kr, const float* __restrict__ Vbuf,
        float* __restrict__ KVpart) {
    int blk = blockIdx.x;                 // bh*NCH + ch
    int bh = blk >> 4, ch = blk & 15;
    int b = bh >> 4, h = bh & 15;
    int e = threadIdx.x & 63;             // V column
    int dq = threadIdx.x >> 6;            // 0..3 (d quarter); == wave
    int rr = threadIdx.x >> 4;            // 0..15 staging row
    int c8 = threadIdx.x & 15;            // float4 slot within row
    __shared__ float sh[2][2][16][64];    // [buf][K/V][row][col] = 16 KB
    const size_t rb = (size_t)(b * Tq + ch * CHT);
    const size_t coloff = h * 64 + c8 * 4;
    gload16(&Kr[(rb + rr) * 1024 + coloff], &sh[0][0][dq * 4][0]);
    gload16(&Vbuf[(rb + rr) * 1024 + coloff], &sh[0][1][dq * 4][0]);
    __syncthreads();
    float acc[16] = {};
    for (int st = 0; st < 8; ++st) {
        int cur = st & 1;
        if (st < 7) {   // stage next chunk while computing current
            size_t row = rb + (size_t)(st + 1) * 16 + rr;
            gload16(&Kr[row * 1024 + coloff], &sh[cur ^ 1][0][dq * 4][0]);
            gload16(&Vbuf[row * 1024 + coloff], &sh[cur ^ 1][1][dq * 4][0]);
        }
        #pragma unroll
        for (int r = 0; r < 16; ++r) {
            float vv = sh[cur][1][r][e];
            #pragma unroll
            for (int i = 0; i < 16; ++i)
                acc[i] += sh[cur][0][r][dq * 16 + i] * vv;
        }
        __syncthreads();
    }
    float* out = KVpart + (size_t)blk * 4096;
    #pragma unroll
    for (int i = 0; i < 16; ++i) out[(dq * 16 + i) * 64 + e] = acc[i];
}

// ---------------- merged reduce: KV over chunks + Ksum over row-blocks ----------------
__global__ __launch_bounds__(256) void reduce_kernel(
        const float* __restrict__ KVpart, float* __restrict__ KV,
        const float* __restrict__ Kpart, float* __restrict__ Ksum) {
    int gid = blockIdx.x;
    if (gid < 512) {
        int idx = gid * 256 + threadIdx.x;       // < B*H*4096 = 131072
        int bh = idx >> 12;
        int i = idx & 4095;
        float s = 0.f;
        #pragma unroll
        for (int ch = 0; ch < NCH; ++ch) s += KVpart[((size_t)(bh * NCH + ch)) * 4096 + i];
        KV[idx] = s;
    } else {
        int idx = (gid - 512) * 256 + threadIdx.x;    // < 2048
        if (idx >= Bq * 1024) return;
        int b = idx >> 10, c = idx & 1023;
        float s = 0.f;
        #pragma unroll
        for (int mb = 0; mb < 16; ++mb) s += Kpart[(size_t)(b * 16 + mb) * 1024 + c];
        Ksum[idx] = s;
    }
}

// ---------------- y = (Qr @ KV) / denom, 8 rows/block, KV staged per head ----------------
// R15/R16-proven form (2 rows/wave keeps the d-loop batch-unrolled; 4 rows/wave
// made the compiler emit a serial LDS-load chain -- R17 regression, VGPR=32 tell).
__global__ __launch_bounds__(256) void y_split_kernel(
        const float* __restrict__ Qr, const float* __restrict__ KV,
        const float* __restrict__ Ksum, const float* __restrict__ cosT,
        const float* __restrict__ sinT, unsigned short* __restrict__ hi,
        unsigned short* __restrict__ lo) {
    int row0 = blockIdx.x * 8;            // 8 consecutive rows, same batch b
    int b = row0 >> 11;
    int lane = threadIdx.x & 63, w = threadIdx.x >> 6;
    __shared__ float skv[64][64];         // 16 KB: KV[b,h]
    __shared__ float sq[8][64];           // 2 KB: 8 q-rows of head h
    for (int h = 0; h < Hq; ++h) {
        __syncthreads();                  // protect prev-iter LDS reads
        const float* kvp = KV + (size_t)(b * Hq + h) * 4096;
        #pragma unroll
        for (int i = 0; i < 4; ++i) {
            int idx = threadIdx.x + i * 256;
            ((float4*)skv)[idx] = ((const float4*)kvp)[idx];
        }
        #pragma unroll
        for (int i = 0; i < 2; ++i) {
            int idx = threadIdx.x + i * 256;
            int r = idx >> 6, d = idx & 63;
            sq[r][d] = Qr[(size_t)(row0 + r) * 1024 + h * 64 + d];
        }
        __syncthreads();
        #pragma unroll
        for (int rr = 0; rr < 2; ++rr) {
            int r = (w << 1) + rr;
            int t = (row0 + r) & (Tq - 1);
            float qv = sq[r][lane];
            float c = cosT[t * 32 + (lane & 31)];
            float s = sinT[t * 32 + (lane & 31)];
            float sgn = (lane & 32) ? 1.0f : -1.0f;
            float kc = Ksum[b * 1024 + h * 64 + lane];
            float kp = Ksum[b * 1024 + h * 64 + (lane ^ 32)];
            float dn = qv * (kc * c + sgn * kp * s);
            #pragma unroll
            for (int off = 32; off; off >>= 1) dn += __shfl_xor(dn, off);
            float acc = 0.f;
            #pragma unroll
            for (int d = 0; d < 64; ++d) acc += sq[r][d] * skv[d][lane];
            float v = acc / dn;
            unsigned short hb = bf16_rne(v);
            float hf = __uint_as_float((unsigned int)hb << 16);
            hi[(size_t)(row0 + r) * 1024 + h * 64 + lane] = hb;
            lo[(size_t)(row0 + r) * 1024 + h * 64 + lane] = bf16_rne(v - hf);
        }
    }
}

extern "C" void kernel_launch(void* const* d_in, const int* in_sizes, int n_in,
                              void* d_out, int out_size, void* d_ws, size_t ws_size,
                              hipStream_t stream) {
    const float* x      = (const float*)d_in[0];
    const float* w_attn = (const float*)d_in[1];
    const float* b_attn = (const float*)d_in[2];
    const float* w_proj = (const float*)d_in[3];
    const float* b_proj = (const float*)d_in[4];
    float* out = (float*)d_out;

    float* ws = (float*)d_ws;
    float* Qr    = ws;                           // 4,194,304
    float* Kr    = Qr + (size_t)NROW * Cq;       // 4,194,304
    float* Vb    = Kr + (size_t)NROW * Cq;       // 4,194,304
    float* cosT  = Vb + (size_t)NROW * Cq;       // 65,536
    float* sinT  = cosT + Tq * 32;               // 65,536
    float* Kpart = sinT + Tq * 32;               // 32,768
    float* Ksum  = Kpart + 32 * 1024;            // 2,048
    float* KVp   = Ksum + 2048;                  // 2,097,152 (512*4096)
    float* KV    = KVp + (size_t)512 * 4096;     // 131,072
    unsigned short* xhi  = (unsigned short*)(KV + 131072);   // reused for x then y
    unsigned short* xlo  = xhi + (size_t)NROW * Cq;
    unsigned short* wahi = xlo + (size_t)NROW * Cq;          // 3,145,728
    unsigned short* walo = wahi + (size_t)N3C * Cq;
    unsigned short* wphi = walo + (size_t)N3C * Cq;          // 1,048,576
    unsigned short* wplo = wphi + (size_t)Cq * Cq;

    // 1. merged prep: rope tables + x split + w_attn^T split + w_proj^T split
    prep_kernel<<<256 + 4096 + 3072 + 1024, 256, 0, stream>>>(
        x, w_attn, w_proj, cosT, sinT, xhi, xlo, wahi, walo, wphi, wplo);

    // 2. qkv GEMM (bf16x3, BK=64) with fused elu+rope epilogue -> Qr, Kr, Vb, Kpart
    gemm_qkv_kernel<<<dim3(N3C / 128, NROW / 128), 512, 0, stream>>>(
        xhi, xlo, wahi, walo, b_attn, Qr, Kr, Vb, Kpart, cosT, sinT);

    // 3. KV = Kr^T @ V per head (async 2-phase staging)
    kv_kernel<<<Bq * Hq * NCH, 256, 0, stream>>>(Kr, Vb, KVp);

    // 4. merged reduce: KV chunks + Ksum row-blocks
    reduce_kernel<<<512 + 8, 256, 0, stream>>>(KVp, KV, Kpart, Ksum);

    // 5. y = Qr @ KV / denom (denom fused), bf16 hi/lo split (A of proj GEMM)
    y_split_kernel<<<NROW / 8, 256, 0, stream>>>(Qr, KV, Ksum, cosT, sinT, xhi, xlo);

    // 6. out = y @ w_proj + b_proj  (128x64 tile, 512 blocks = 2/CU)
    gemm_proj_kernel<<<dim3(Cq / 64, NROW / 128), 512, 0, stream>>>(
        xhi, xlo, wphi, wplo, b_proj, out);
}

// Round 20
// 176.375 us; speedup vs baseline: 1.6061x; 1.0276x over previous
//
#include <hip/hip_runtime.h>
#include <hip/hip_bf16.h>

// Problem constants (fixed by setup_inputs)
#define Bq 2
#define Tq 2048
#define Cq 1024
#define Hq 16
#define N3C 3072
#define NROW 4096

typedef __attribute__((ext_vector_type(8))) __bf16 bf16x8;
typedef __attribute__((ext_vector_type(4))) float f32x4;

__device__ __forceinline__ float elu1(float x) {
    return x > 0.0f ? x + 1.0f : __expf(x);
}

// round-to-nearest-even fp32 -> bf16 bits (finite inputs)
__device__ __forceinline__ unsigned short bf16_rne(float v) {
    unsigned int u = __float_as_uint(v);
    u += 0x7FFFu + ((u >> 16) & 1u);
    return (unsigned short)(u >> 16);
}

// ---------------- merged prep: rope table + A split + both B^T splits ----------------
__global__ __launch_bounds__(256) void prep_kernel(
        const float* __restrict__ x, const float* __restrict__ w_attn,
        const float* __restrict__ w_proj,
        float* __restrict__ cosT, float* __restrict__ sinT,
        unsigned short* __restrict__ xhi, unsigned short* __restrict__ xlo,
        unsigned short* __restrict__ wahi, unsigned short* __restrict__ walo,
        unsigned short* __restrict__ wphi, unsigned short* __restrict__ wplo) {
    int blk = blockIdx.x;
    if (blk < 256) {
        int idx = blk * 256 + threadIdx.x;       // < T*32
        int t = idx >> 5;
        int i = idx & 31;
        double inv = pow(10000.0, -(double)i / 32.0);
        double ang = (double)t * inv;
        cosT[idx] = (float)cos(ang);
        sinT[idx] = (float)sin(ang);
    } else if (blk < 256 + 4096) {
        int idx = (blk - 256) * 256 + threadIdx.x;   // < NROW*Cq/4
        float4 v = ((const float4*)x)[idx];
        float a[4] = {v.x, v.y, v.z, v.w};
        unsigned short hb[4], lb[4];
        #pragma unroll
        for (int i = 0; i < 4; ++i) {
            hb[i] = bf16_rne(a[i]);
            float hf = __uint_as_float((unsigned int)hb[i] << 16);
            lb[i] = bf16_rne(a[i] - hf);
        }
        ((ushort4*)xhi)[idx] = make_ushort4(hb[0], hb[1], hb[2], hb[3]);
        ((ushort4*)xlo)[idx] = make_ushort4(lb[0], lb[1], lb[2], lb[3]);
    } else {
        const float* B;
        unsigned short *hi, *lo;
        int bx, by, N;
        if (blk < 256 + 4096 + 3072) {
            int bid = blk - (256 + 4096);
            B = w_attn; hi = wahi; lo = walo; N = N3C;
            bx = bid % 96; by = bid / 96;
        } else {
            int bid = blk - (256 + 4096 + 3072);
            B = w_proj; hi = wphi; lo = wplo; N = Cq;
            bx = bid % 32; by = bid / 32;
        }
        __shared__ float tile[32][33];            // tile[k][n]
        int tx = threadIdx.x & 31, ty = threadIdx.x >> 5;    // ty 0..7
        int k0 = by * 32, n0 = bx * 32;
        #pragma unroll
        for (int i = 0; i < 4; ++i)
            tile[ty + i * 8][tx] = B[(size_t)(k0 + ty + i * 8) * N + n0 + tx];
        __syncthreads();
        // vectorized transposed store: thread covers (n, 4 consecutive k)
        int nl = threadIdx.x >> 3;                // 0..31
        int kq = (threadIdx.x & 7) << 2;          // 0,4,...,28
        unsigned short hb[4], lb[4];
        #pragma unroll
        for (int j = 0; j < 4; ++j) {
            float v = tile[kq + j][nl];
            hb[j] = bf16_rne(v);
            float hf = __uint_as_float((unsigned int)hb[j] << 16);
            lb[j] = bf16_rne(v - hf);
        }
        size_t base = (size_t)(n0 + nl) * Cq + k0 + kq;
        *(ushort4*)(hi + base) = make_ushort4(hb[0], hb[1], hb[2], hb[3]);
        *(ushort4*)(lo + base) = make_ushort4(lb[0], lb[1], lb[2], lb[3]);
    }
}

// ---------------- async global->LDS, 16B per lane ----------------
__device__ __forceinline__ void gload16(const void* g, void* l) {
    __builtin_amdgcn_global_load_lds(
        (const __attribute__((address_space(1))) void*)g,
        (__attribute__((address_space(3))) void*)l, 16, 0, 0);
}

// ---------------- qkv split-3 GEMM, K=1024, BK=64, fused elu/rope/colsum epilogue ----------------
// R19-proven: two 32-col LDS planes per stream, 8 gloads/thread/K-tile,
// barriers halved vs BK=32. Tile 128x128, 8 waves (4Mx2N), 2x4 frags/wave.
// T2 swizzle both-sides per plane. LDS 64 KB -> 2 blocks/CU x 8 waves.
__global__ __launch_bounds__(512, 4) void gemm_qkv_kernel(
        const unsigned short* __restrict__ Ahi, const unsigned short* __restrict__ Alo,
        const unsigned short* __restrict__ Bhi, const unsigned short* __restrict__ Blo,
        const float* __restrict__ bias,
        float* __restrict__ Qr, float* __restrict__ Kr, float* __restrict__ Vbuf,
        float* __restrict__ Kpart, const float* __restrict__ cosT,
        const float* __restrict__ sinT) {
    __shared__ unsigned short sAh[2][128][32];
    __shared__ unsigned short sAl[2][128][32];
    __shared__ unsigned short sBh[2][128][32];
    __shared__ unsigned short sBl[2][128][32];

    const int tid = threadIdx.x;
    const int lane = tid & 63;
    const int wave = tid >> 6;            // 0..7
    const int wr = wave >> 1, wc = wave & 1;   // 4 M-quarters x 2 N-halves
    const int brow = blockIdx.y * 128;
    const int bcol = blockIdx.x * 128;

    const int r_lo = tid >> 2;
    const int skc = (((tid & 3) ^ ((tid >> 3) & 3)) << 3);  // pre-swizzled global k offset

    const int fr = lane & 15;
    const int sgx = (((lane >> 4) ^ ((fr >> 1) & 3)) << 3);  // swizzled read slot
    const int qrow = (lane >> 4) << 2;

    f32x4 acc[2][4];
    #pragma unroll
    for (int i = 0; i < 2; ++i)
        #pragma unroll
        for (int j = 0; j < 4; ++j)
            acc[i][j] = (f32x4){0.0f, 0.0f, 0.0f, 0.0f};

    for (int k0 = 0; k0 < Cq; k0 += 64) {
        size_t ga = (size_t)(brow + r_lo) * Cq + k0 + skc;
        size_t gb = (size_t)(bcol + r_lo) * Cq + k0 + skc;
        gload16(Ahi + ga, &sAh[0][wave << 4][0]);
        gload16(Ahi + ga + 32, &sAh[1][wave << 4][0]);
        gload16(Alo + ga, &sAl[0][wave << 4][0]);
        gload16(Alo + ga + 32, &sAl[1][wave << 4][0]);
        gload16(Bhi + gb, &sBh[0][wave << 4][0]);
        gload16(Bhi + gb + 32, &sBh[1][wave << 4][0]);
        gload16(Blo + gb, &sBl[0][wave << 4][0]);
        gload16(Blo + gb + 32, &sBl[1][wave << 4][0]);
        __syncthreads();

        #pragma unroll
        for (int kh = 0; kh < 2; ++kh) {
            bf16x8 ah[2], al[2], bh[4], bl[4];
            #pragma unroll
            for (int i = 0; i < 2; ++i) {
                ah[i] = *(const bf16x8*)&sAh[kh][(wr << 5) + (i << 4) + fr][sgx];
                al[i] = *(const bf16x8*)&sAl[kh][(wr << 5) + (i << 4) + fr][sgx];
            }
            #pragma unroll
            for (int j = 0; j < 4; ++j) {
                bh[j] = *(const bf16x8*)&sBh[kh][(wc << 6) + (j << 4) + fr][sgx];
                bl[j] = *(const bf16x8*)&sBl[kh][(wc << 6) + (j << 4) + fr][sgx];
            }
            #pragma unroll
            for (int i = 0; i < 2; ++i)
                #pragma unroll
                for (int j = 0; j < 4; ++j) {
                    acc[i][j] = __builtin_amdgcn_mfma_f32_16x16x32_bf16(ah[i], bh[j], acc[i][j], 0, 0, 0);
                    acc[i][j] = __builtin_amdgcn_mfma_f32_16x16x32_bf16(ah[i], bl[j], acc[i][j], 0, 0, 0);
                    acc[i][j] = __builtin_amdgcn_mfma_f32_16x16x32_bf16(al[i], bh[j], acc[i][j], 0, 0, 0);
                }
        }
        __syncthreads();
    }

    // ---- fused epilogue ----  C/D layout: col = lane&15, row = (lane>>4)*4 + q
    int region = bcol >> 10;                  // 0=Q 1=K 2=V
    if (region == 2) {
        #pragma unroll
        for (int j = 0; j < 4; ++j) {
            int n3 = bcol + (wc << 6) + (j << 4) + fr;
            float bv = bias[n3];
            int nc = n3 & 1023;
            #pragma unroll
            for (int i = 0; i < 2; ++i) {
                int m = brow + (wr << 5) + (i << 4) + qrow;
                #pragma unroll
                for (int q = 0; q < 4; ++q)
                    Vbuf[(size_t)(m + q) * 1024 + nc] = acc[i][j][q] + bv;
            }
        }
    } else {
        float* dst = (region == 0) ? Qr : Kr;
        float colsum[4] = {0.f, 0.f, 0.f, 0.f};
        #pragma unroll
        for (int i = 0; i < 2; ++i) {
            float e[4][4];
            #pragma unroll
            for (int j = 0; j < 4; ++j) {
                float bv = bias[bcol + (wc << 6) + (j << 4) + fr];
                #pragma unroll
                for (int q = 0; q < 4; ++q)
                    e[j][q] = elu1(acc[i][j][q] + bv);
            }
            #pragma unroll
            for (int j = 0; j < 4; ++j) {
                int n3 = bcol + (wc << 6) + (j << 4) + fr;
                int nc = n3 & 1023;
                float sgn = (j < 2) ? -1.0f : 1.0f;
                int fidx = ((j & 1) << 4) + fr;   // (dcol & 31)
                int mbase = brow + (wr << 5) + (i << 4) + qrow;
                #pragma unroll
                for (int q = 0; q < 4; ++q) {
                    int m = mbase + q;
                    int t = m & (Tq - 1);
                    float c = cosT[t * 32 + fidx];
                    float s = sinT[t * 32 + fidx];
                    float r = e[j][q] * c + sgn * e[j ^ 2][q] * s;
                    dst[(size_t)m * 1024 + nc] = r;
                    if (region == 1) colsum[j] += e[j][q];
                }
            }
        }
        if (region == 1) {
            // deterministic per-block column-sum (128 cols x 16 partials)
            float* kred = (float*)&sAh[0][0][0];  // 8KB of the 16KB sAh
            int slot = (wr << 2) + (lane >> 4);   // 0..15
            #pragma unroll
            for (int j = 0; j < 4; ++j) {
                int cl = (wc << 6) + (j << 4) + fr;
                kred[cl * 16 + slot] = colsum[j];
            }
            __syncthreads();
            if (tid < 128) {
                float s2 = 0.f;
                #pragma unroll
                for (int u = 0; u < 16; ++u) s2 += kred[tid * 16 + u];
                Kpart[(brow >> 7) * 1024 + (bcol & 1023) + tid] = s2;
            }
        }
    }
}

// ---------------- proj split-3 GEMM, K=1024, tile 128x64, BK=64 ----------------
// R19's barrier-halving applied to proj: two 32-col planes per stream,
// 32 barriers vs 64. Grid 512 blocks = 2/CU (LDS 48 KB doesn't bind at 2/CU).
__global__ __launch_bounds__(512, 4) void gemm_proj_kernel(
        const unsigned short* __restrict__ Ahi, const unsigned short* __restrict__ Alo,
        const unsigned short* __restrict__ Bhi, const unsigned short* __restrict__ Blo,
        const float* __restrict__ bias, float* __restrict__ C) {
    __shared__ unsigned short sAh[2][128][32];
    __shared__ unsigned short sAl[2][128][32];
    __shared__ unsigned short sBh[2][64][32];
    __shared__ unsigned short sBl[2][64][32];

    const int tid = threadIdx.x;
    const int lane = tid & 63;
    const int wave = tid >> 6;            // 0..7
    const int wr = wave >> 1, wc = wave & 1;   // 4 M-quarters x 2 N-halves (32 cols each)
    const int brow = blockIdx.y * 128;
    const int bcol = blockIdx.x * 64;

    const int r_lo = tid >> 2;                              // 0..127
    const int skc = (((tid & 3) ^ ((tid >> 3) & 3)) << 3);  // pre-swizzled global k offset

    const int fr = lane & 15;
    const int sgx = (((lane >> 4) ^ ((fr >> 1) & 3)) << 3);
    const int qrow = (lane >> 4) << 2;

    f32x4 acc[2][2];
    #pragma unroll
    for (int i = 0; i < 2; ++i)
        #pragma unroll
        for (int j = 0; j < 2; ++j)
            acc[i][j] = (f32x4){0.0f, 0.0f, 0.0f, 0.0f};

    for (int k0 = 0; k0 < Cq; k0 += 64) {
        size_t ga = (size_t)(brow + r_lo) * Cq + k0 + skc;
        gload16(Ahi + ga, &sAh[0][wave << 4][0]);
        gload16(Ahi + ga + 32, &sAh[1][wave << 4][0]);
        gload16(Alo + ga, &sAl[0][wave << 4][0]);
        gload16(Alo + ga + 32, &sAl[1][wave << 4][0]);
        if (tid < 256) {                                    // 64 B-rows x 4 slots
            size_t gb = (size_t)(bcol + r_lo) * Cq + k0 + skc;
            gload16(Bhi + gb, &sBh[0][wave << 4][0]);
            gload16(Bhi + gb + 32, &sBh[1][wave << 4][0]);
            gload16(Blo + gb, &sBl[0][wave << 4][0]);
            gload16(Blo + gb + 32, &sBl[1][wave << 4][0]);
        }
        __syncthreads();

        #pragma unroll
        for (int kh = 0; kh < 2; ++kh) {
            bf16x8 ah[2], al[2], bh[2], bl[2];
            #pragma unroll
            for (int i = 0; i < 2; ++i) {
                ah[i] = *(const bf16x8*)&sAh[kh][(wr << 5) + (i << 4) + fr][sgx];
                al[i] = *(const bf16x8*)&sAl[kh][(wr << 5) + (i << 4) + fr][sgx];
            }
            #pragma unroll
            for (int j = 0; j < 2; ++j) {
                bh[j] = *(const bf16x8*)&sBh[kh][(wc << 5) + (j << 4) + fr][sgx];
                bl[j] = *(const bf16x8*)&sBl[kh][(wc << 5) + (j << 4) + fr][sgx];
            }
            #pragma unroll
            for (int i = 0; i < 2; ++i)
                #pragma unroll
                for (int j = 0; j < 2; ++j) {
                    acc[i][j] = __builtin_amdgcn_mfma_f32_16x16x32_bf16(ah[i], bh[j], acc[i][j], 0, 0, 0);
                    acc[i][j] = __builtin_amdgcn_mfma_f32_16x16x32_bf16(ah[i], bl[j], acc[i][j], 0, 0, 0);
                    acc[i][j] = __builtin_amdgcn_mfma_f32_16x16x32_bf16(al[i], bh[j], acc[i][j], 0, 0, 0);
                }
        }
        __syncthreads();
    }

    #pragma unroll
    for (int j = 0; j < 2; ++j) {
        int n = bcol + (wc << 5) + (j << 4) + fr;
        float bv = bias[n];
        #pragma unroll
        for (int i = 0; i < 2; ++i) {
            int m = brow + (wr << 5) + (i << 4) + qrow;
            #pragma unroll
            for (int q = 0; q < 4; ++q)
                C[(size_t)(m + q) * Cq + n] = acc[i][j][q] + bv;
        }
    }
}

// ---------------- KV partial: per (b,h,chunk of 128 rows) ----------------
#define NCH 16
#define CHT (Tq / NCH)    // 128
__global__ __launch_bounds__(256) void kv_kernel(
        const float* __restrict__ Kr, const float* __restrict__ Vbuf,
        float* __restrict__ KVpart) {
    int blk = blockIdx.x;                 // bh*NCH + ch
    int bh = blk >> 4, ch = blk & 15;
    int b = bh >> 4, h = bh & 15;
    int e = threadIdx.x & 63;             // V column
    int dq = threadIdx.x >> 6;            // 0..3 (d quarter); == wave
    int rr = threadIdx.x >> 4;            // 0..15 staging row
    int c8 = threadIdx.x & 15;            // float4 slot within row
    __shared__ float sh[2][2][16][64];    // [buf][K/V][row][col] = 16 KB
    const size_t rb = (size_t)(b * Tq + ch * CHT);
    const size_t coloff = h * 64 + c8 * 4;
    gload16(&Kr[(rb + rr) * 1024 + coloff], &sh[0][0][dq * 4][0]);
    gload16(&Vbuf[(rb + rr) * 1024 + coloff], &sh[0][1][dq * 4][0]);
    __syncthreads();
    float acc[16] = {};
    for (int st = 0; st < 8; ++st) {
        int cur = st & 1;
        if (st < 7) {   // stage next chunk while computing current
            size_t row = rb + (size_t)(st + 1) * 16 + rr;
            gload16(&Kr[row * 1024 + coloff], &sh[cur ^ 1][0][dq * 4][0]);
            gload16(&Vbuf[row * 1024 + coloff], &sh[cur ^ 1][1][dq * 4][0]);
        }
        #pragma unroll
        for (int r = 0; r < 16; ++r) {
            float vv = sh[cur][1][r][e];
            #pragma unroll
            for (int i = 0; i < 16; ++i)
                acc[i] += sh[cur][0][r][dq * 16 + i] * vv;
        }
        __syncthreads();
    }
    float* out = KVpart + (size_t)blk * 4096;
    #pragma unroll
    for (int i = 0; i < 16; ++i) out[(dq * 16 + i) * 64 + e] = acc[i];
}

// ---------------- merged reduce: KV over chunks + Ksum over row-blocks ----------------
__global__ __launch_bounds__(256) void reduce_kernel(
        const float* __restrict__ KVpart, float* __restrict__ KV,
        const float* __restrict__ Kpart, float* __restrict__ Ksum) {
    int gid = blockIdx.x;
    if (gid < 512) {
        int idx = gid * 256 + threadIdx.x;       // < B*H*4096 = 131072
        int bh = idx >> 12;
        int i = idx & 4095;
        float s = 0.f;
        #pragma unroll
        for (int ch = 0; ch < NCH; ++ch) s += KVpart[((size_t)(bh * NCH + ch)) * 4096 + i];
        KV[idx] = s;
    } else {
        int idx = (gid - 512) * 256 + threadIdx.x;    // < 2048
        if (idx >= Bq * 1024) return;
        int b = idx >> 10, c = idx & 1023;
        float s = 0.f;
        #pragma unroll
        for (int mb = 0; mb < 16; ++mb) s += Kpart[(size_t)(b * 16 + mb) * 1024 + c];
        Ksum[idx] = s;
    }
}

// ---------------- y = (Qr @ KV) / denom, 8 rows/block, KV staged per head ----------------
// R15/R16-proven form (2 rows/wave keeps the d-loop batch-unrolled; 4 rows/wave
// made the compiler emit a serial LDS-load chain -- R17 regression, VGPR=32 tell).
__global__ __launch_bounds__(256) void y_split_kernel(
        const float* __restrict__ Qr, const float* __restrict__ KV,
        const float* __restrict__ Ksum, const float* __restrict__ cosT,
        const float* __restrict__ sinT, unsigned short* __restrict__ hi,
        unsigned short* __restrict__ lo) {
    int row0 = blockIdx.x * 8;            // 8 consecutive rows, same batch b
    int b = row0 >> 11;
    int lane = threadIdx.x & 63, w = threadIdx.x >> 6;
    __shared__ float skv[64][64];         // 16 KB: KV[b,h]
    __shared__ float sq[8][64];           // 2 KB: 8 q-rows of head h
    for (int h = 0; h < Hq; ++h) {
        __syncthreads();                  // protect prev-iter LDS reads
        const float* kvp = KV + (size_t)(b * Hq + h) * 4096;
        #pragma unroll
        for (int i = 0; i < 4; ++i) {
            int idx = threadIdx.x + i * 256;
            ((float4*)skv)[idx] = ((const float4*)kvp)[idx];
        }
        #pragma unroll
        for (int i = 0; i < 2; ++i) {
            int idx = threadIdx.x + i * 256;
            int r = idx >> 6, d = idx & 63;
            sq[r][d] = Qr[(size_t)(row0 + r) * 1024 + h * 64 + d];
        }
        __syncthreads();
        #pragma unroll
        for (int rr = 0; rr < 2; ++rr) {
            int r = (w << 1) + rr;
            int t = (row0 + r) & (Tq - 1);
            float qv = sq[r][lane];
            float c = cosT[t * 32 + (lane & 31)];
            float s = sinT[t * 32 + (lane & 31)];
            float sgn = (lane & 32) ? 1.0f : -1.0f;
            float kc = Ksum[b * 1024 + h * 64 + lane];
            float kp = Ksum[b * 1024 + h * 64 + (lane ^ 32)];
            float dn = qv * (kc * c + sgn * kp * s);
            #pragma unroll
            for (int off = 32; off; off >>= 1) dn += __shfl_xor(dn, off);
            float acc = 0.f;
            #pragma unroll
            for (int d = 0; d < 64; ++d) acc += sq[r][d] * skv[d][lane];
            float v = acc / dn;
            unsigned short hb = bf16_rne(v);
            float hf = __uint_as_float((unsigned int)hb << 16);
            hi[(size_t)(row0 + r) * 1024 + h * 64 + lane] = hb;
            lo[(size_t)(row0 + r) * 1024 + h * 64 + lane] = bf16_rne(v - hf);
        }
    }
}

extern "C" void kernel_launch(void* const* d_in, const int* in_sizes, int n_in,
                              void* d_out, int out_size, void* d_ws, size_t ws_size,
                              hipStream_t stream) {
    const float* x      = (const float*)d_in[0];
    const float* w_attn = (const float*)d_in[1];
    const float* b_attn = (const float*)d_in[2];
    const float* w_proj = (const float*)d_in[3];
    const float* b_proj = (const float*)d_in[4];
    float* out = (float*)d_out;

    float* ws = (float*)d_ws;
    float* Qr    = ws;                           // 4,194,304
    float* Kr    = Qr + (size_t)NROW * Cq;       // 4,194,304
    float* Vb    = Kr + (size_t)NROW * Cq;       // 4,194,304
    float* cosT  = Vb + (size_t)NROW * Cq;       // 65,536
    float* sinT  = cosT + Tq * 32;               // 65,536
    float* Kpart = sinT + Tq * 32;               // 32,768
    float* Ksum  = Kpart + 32 * 1024;            // 2,048
    float* KVp   = Ksum + 2048;                  // 2,097,152 (512*4096)
    float* KV    = KVp + (size_t)512 * 4096;     // 131,072
    unsigned short* xhi  = (unsigned short*)(KV + 131072);   // reused for x then y
    unsigned short* xlo  = xhi + (size_t)NROW * Cq;
    unsigned short* wahi = xlo + (size_t)NROW * Cq;          // 3,145,728
    unsigned short* walo = wahi + (size_t)N3C * Cq;
    unsigned short* wphi = walo + (size_t)N3C * Cq;          // 1,048,576
    unsigned short* wplo = wphi + (size_t)Cq * Cq;

    // 1. merged prep: rope tables + x split + w_attn^T split + w_proj^T split
    prep_kernel<<<256 + 4096 + 3072 + 1024, 256, 0, stream>>>(
        x, w_attn, w_proj, cosT, sinT, xhi, xlo, wahi, walo, wphi, wplo);

    // 2. qkv GEMM (bf16x3, BK=64) with fused elu+rope epilogue -> Qr, Kr, Vb, Kpart
    gemm_qkv_kernel<<<dim3(N3C / 128, NROW / 128), 512, 0, stream>>>(
        xhi, xlo, wahi, walo, b_attn, Qr, Kr, Vb, Kpart, cosT, sinT);

    // 3. KV = Kr^T @ V per head (async 2-phase staging)
    kv_kernel<<<Bq * Hq * NCH, 256, 0, stream>>>(Kr, Vb, KVp);

    // 4. merged reduce: KV chunks + Ksum row-blocks
    reduce_kernel<<<512 + 8, 256, 0, stream>>>(KVp, KV, Kpart, Ksum);

    // 5. y = Qr @ KV / denom (denom fused), bf16 hi/lo split (A of proj GEMM)
    y_split_kernel<<<NROW / 8, 256, 0, stream>>>(Qr, KV, Ksum, cosT, sinT, xhi, xlo);

    // 6. out = y @ w_proj + b_proj  (128x64 tile, BK=64, 512 blocks = 2/CU)
    gemm_proj_kernel<<<dim3(Cq / 64, NROW / 128), 512, 0, stream>>>(
        xhi, xlo, wphi, wplo, b_proj, out);
}